// Round 10
// baseline (49.163 us; speedup 1.0000x reference)
//
#include <hip/hip_runtime.h>
#include <math.h>

#define BB 2
#define NAT 2048
#define NTOK 256
#define POISON 1.0e8f
#define NBLK 1024

#if __has_builtin(__builtin_amdgcn_sqrtf)
#define FSQRT __builtin_amdgcn_sqrtf
#else
#define FSQRT sqrtf
#endif
#if __has_builtin(__builtin_amdgcn_exp2f)
#define FEXP2 __builtin_amdgcn_exp2f
#else
#define FEXP2 exp2f
#endif

struct WS {
  double mom[NBLK][17];       // per-prep-block moment partials
  double partials[4 * NBLK];  // SoA {bond_num, bond_den, cem, cm} per main-block
  double mse_b[BB];
  double red0[BB];            // per-batch masked-atom count n
  int ticket;
  int pad;
  float wA[BB*NAT];
  float nucA[BB*NAT];
  float ligA[BB*NAT];
  // px = {x,y,z, bitcast(tok | polbit<<8)}, pg = {gx,gy,gz, mask}; masked atoms poisoned
  float4 px[BB*NAT];
  float4 pg[BB*NAT];
};

// ---------------- K1: pack (one wave per atom) + per-block moment partials ----------------
__global__ __launch_bounds__(256) void k_prep(
    const float* __restrict__ x, const float* __restrict__ xgt,
    const float* __restrict__ mask, const float* __restrict__ A,
    const float* __restrict__ poly, const float* __restrict__ lig,
    const float* __restrict__ dna, const float* __restrict__ rna,
    WS* __restrict__ ws) {
  int tid = threadIdx.x, lane = tid & 63, wv = tid >> 6, blk = blockIdx.x;
  int gid = blk * 4 + wv;                  // atom index
  int b = gid >> 11;
  float4 v = ((const float4*)(A + (size_t)gid * NTOK))[lane];
  float s = v.x * (float)(4*lane) + v.y * (float)(4*lane+1)
          + v.z * (float)(4*lane+2) + v.w * (float)(4*lane+3);
  for (int off = 32; off; off >>= 1) s += __shfl_xor(s, off);
  __shared__ double smom[4][17];
  if (lane == 0) {
    int t = (int)(s + 0.5f);
    float d  = dna[b*NTOK + t], r = rna[b*NTOK + t];
    float li = lig[b*NTOK + t], po = poly[b*NTOK + t];
    float m  = mask[gid];
    bool ok = (m != 0.0f);
    float w = 1.0f + 5.0f*d + 5.0f*r + 10.0f*li;
    ws->wA[gid]   = w;
    ws->nucA[gid] = d + r;
    ws->ligA[gid] = li;
    int meta = t | ((po != 0.0f && ok) ? 256 : 0);
    const float* xp = x   + (size_t)gid * 3;
    const float* gp = xgt + (size_t)gid * 3;
    float x0 = xp[0], x1 = xp[1], x2 = xp[2];
    float g0 = gp[0], g1 = gp[1], g2 = gp[2];
    ws->px[gid] = ok ? make_float4(x0, x1, x2, __int_as_float(meta))
                     : make_float4(POISON, POISON, POISON, __int_as_float(meta));
    ws->pg[gid] = ok ? make_float4(g0, g1, g2, m)
                     : make_float4(POISON, POISON, POISON, m);
    // moment contributions (wm = 0 for masked atoms kills every term)
    double wm = (double)(w * m);
    double X0 = x0, X1 = x1, X2 = x2, G0 = g0, G1 = g1, G2 = g2;
    smom[wv][0] = (double)m;
    smom[wv][1] = wm;
    smom[wv][2] = wm*X0;  smom[wv][3] = wm*X1;  smom[wv][4] = wm*X2;
    smom[wv][5] = wm*G0;  smom[wv][6] = wm*G1;  smom[wv][7] = wm*G2;
    smom[wv][8]  = wm*X0*G0; smom[wv][9]  = wm*X0*G1; smom[wv][10] = wm*X0*G2;
    smom[wv][11] = wm*X1*G0; smom[wv][12] = wm*X1*G1; smom[wv][13] = wm*X1*G2;
    smom[wv][14] = wm*X2*G0; smom[wv][15] = wm*X2*G1; smom[wv][16] = wm*X2*G2;
  }
  __syncthreads();
  if (tid < 17)
    ws->mom[blk][tid] = smom[0][tid] + smom[1][tid] + smom[2][tid] + smom[3][tid];
  if (blk == 0 && tid == 0) ws->ticket = 0;   // visible to k_main via kernel boundary
}

// ---------------- 3x3 SVD (f64 Jacobi) -> R(f32), means ----------------
__device__ void svd3(const double* red, float* Rf, float* muf, float* mugf) {
  double swm = red[1];
  double mug[3] = { red[2]/swm, red[3]/swm, red[4]/swm };  // mean x
  double mu[3]  = { red[5]/swm, red[6]/swm, red[7]/swm };  // mean x_gt
  double H[3][3];
  for (int i = 0; i < 3; i++)
    for (int j = 0; j < 3; j++)
      H[i][j] = red[8 + 3*i + j] - swm * mug[i] * mu[j];
  double Km[3][3];
  for (int i = 0; i < 3; i++)
    for (int j = 0; j < 3; j++)
      Km[i][j] = H[0][i]*H[0][j] + H[1][i]*H[1][j] + H[2][i]*H[2][j];
  double V[3][3] = {{1,0,0},{0,1,0},{0,0,1}};
  for (int sweep = 0; sweep < 8; sweep++) {
    double off2 = Km[0][1]*Km[0][1] + Km[0][2]*Km[0][2] + Km[1][2]*Km[1][2];
    double dia2 = Km[0][0]*Km[0][0] + Km[1][1]*Km[1][1] + Km[2][2]*Km[2][2];
    if (off2 < 1e-26 * dia2 + 1e-300) break;
    for (int p = 0; p < 2; p++) {
      for (int q = p + 1; q < 3; q++) {
        double apq = Km[p][q];
        if (fabs(apq) < 1e-300) continue;
        double theta = (Km[q][q] - Km[p][p]) / (2.0 * apq);
        double t = 1.0 / (fabs(theta) + sqrt(theta*theta + 1.0));
        if (theta < 0) t = -t;
        double c = 1.0 / sqrt(t*t + 1.0), sn = t * c;
        for (int k = 0; k < 3; k++) {
          double akp = Km[k][p], akq = Km[k][q];
          Km[k][p] = c*akp - sn*akq;
          Km[k][q] = sn*akp + c*akq;
        }
        for (int k = 0; k < 3; k++) {
          double apk = Km[p][k], aqk = Km[q][k];
          Km[p][k] = c*apk - sn*aqk;
          Km[q][k] = sn*apk + c*aqk;
        }
        for (int k = 0; k < 3; k++) {
          double vkp = V[k][p], vkq = V[k][q];
          V[k][p] = c*vkp - sn*vkq;
          V[k][q] = sn*vkp + c*vkq;
        }
      }
    }
  }
  double ev[3] = { Km[0][0], Km[1][1], Km[2][2] };
  int id[3] = {0, 1, 2};
  for (int i = 0; i < 2; i++)
    for (int j = i + 1; j < 3; j++)
      if (ev[id[j]] > ev[id[i]]) { int tmp = id[i]; id[i] = id[j]; id[j] = tmp; }
  double Uc[3][3], Vc[3][3], S[3];
  for (int k = 0; k < 3; k++) {
    int e = id[k];
    double v0 = V[0][e], v1 = V[1][e], v2 = V[2][e];
    Vc[k][0] = v0; Vc[k][1] = v1; Vc[k][2] = v2;
    double u0 = H[0][0]*v0 + H[0][1]*v1 + H[0][2]*v2;
    double u1 = H[1][0]*v0 + H[1][1]*v1 + H[1][2]*v2;
    double u2 = H[2][0]*v0 + H[2][1]*v1 + H[2][2]*v2;
    double nrm = sqrt(u0*u0 + u1*u1 + u2*u2);
    S[k] = nrm;
    if (nrm > 1e-12) { u0 /= nrm; u1 /= nrm; u2 /= nrm; }
    Uc[k][0] = u0; Uc[k][1] = u1; Uc[k][2] = u2;
  }
  if (S[2] <= 1e-12 * (S[0] > 0 ? S[0] : 1.0)) {
    Uc[2][0] = Uc[0][1]*Uc[1][2] - Uc[0][2]*Uc[1][1];
    Uc[2][1] = Uc[0][2]*Uc[1][0] - Uc[0][0]*Uc[1][2];
    Uc[2][2] = Uc[0][0]*Uc[1][1] - Uc[0][1]*Uc[1][0];
  }
  double detU = Uc[0][0]*(Uc[1][1]*Uc[2][2]-Uc[1][2]*Uc[2][1])
              - Uc[1][0]*(Uc[0][1]*Uc[2][2]-Uc[0][2]*Uc[2][1])
              + Uc[2][0]*(Uc[0][1]*Uc[1][2]-Uc[0][2]*Uc[1][1]);
  double detV = Vc[0][0]*(Vc[1][1]*Vc[2][2]-Vc[1][2]*Vc[2][1])
              - Vc[1][0]*(Vc[0][1]*Vc[2][2]-Vc[0][2]*Vc[2][1])
              + Vc[2][0]*(Vc[0][1]*Vc[1][2]-Vc[0][2]*Vc[1][1]);
  double dsign = (detU * detV < 0.0) ? -1.0 : 1.0;
  for (int i = 0; i < 3; i++)
    for (int j = 0; j < 3; j++)
      Rf[3*i+j] = (float)(Uc[0][i]*Vc[0][j] + Uc[1][i]*Vc[1][j] + dsign*Uc[2][i]*Vc[2][j]);
  for (int i = 0; i < 3; i++) {
    muf[i]  = (float)mu[i];
    mugf[i] = (float)mug[i];
  }
}

// ---- K2: blocks 0/1 do moments+SVD+MSE; all blocks do pair; last block combines ----
__global__ __launch_bounds__(256, 4) void k_main(const float* __restrict__ tb,
                                                 WS* __restrict__ ws,
                                                 float* __restrict__ out) {
  int tid = threadIdx.x, lane = tid & 63, wv = tid >> 6, blk = blockIdx.x;

  __shared__ float2 lut[256];
  __shared__ double sred[17];
  __shared__ float sR[9], smu[3], smug[3];
  __shared__ double dpart[4][17];
  __shared__ int sticket;
  {
    const float K1 = 0.60653066f, K2 = 0.36787944f, K3 = 0.13533528f, K4 = 0.018315639f;
    const float LOG2E = 1.4426950408889634f;
    float dd0 = (float)tid * 0.0625f;
    float Ea = FEXP2(dd0 * LOG2E);
    float Eb = FEXP2((dd0 + 0.0625f) * LOG2E);
    float e0 = __builtin_amdgcn_rcpf(fmaf(Ea, K1, 1.0f)) + __builtin_amdgcn_rcpf(fmaf(Ea, K2, 1.0f))
             + __builtin_amdgcn_rcpf(fmaf(Ea, K3, 1.0f)) + __builtin_amdgcn_rcpf(fmaf(Ea, K4, 1.0f));
    float e1 = __builtin_amdgcn_rcpf(fmaf(Eb, K1, 1.0f)) + __builtin_amdgcn_rcpf(fmaf(Eb, K2, 1.0f))
             + __builtin_amdgcn_rcpf(fmaf(Eb, K3, 1.0f)) + __builtin_amdgcn_rcpf(fmaf(Eb, K4, 1.0f));
    lut[tid] = make_float2(e0, e1 - e0);
  }
  __syncthreads();

  // ---------- special path: moments reduce + SVD + MSE (blocks 0,1) ----------
  if (blk < BB) {
    int bsp = blk;
    double acc[17];
    for (int k = 0; k < 17; k++) acc[k] = 0.0;
    for (int s2 = bsp * 512 + tid; s2 < (bsp + 1) * 512; s2 += 256)
      for (int k = 0; k < 17; k++) acc[k] += ws->mom[s2][k];
    for (int k = 0; k < 17; k++)
      for (int off = 32; off; off >>= 1) acc[k] += __shfl_xor(acc[k], off);
    if (lane == 0)
      for (int k = 0; k < 17; k++) dpart[wv][k] = acc[k];
    __syncthreads();
    if (tid < 17)
      sred[tid] = dpart[0][tid] + dpart[1][tid] + dpart[2][tid] + dpart[3][tid];
    __syncthreads();
    if (tid == 0) svd3(sred, sR, smu, smug);
    __syncthreads();
    double msea = 0.0;
    for (int a2 = tid; a2 < NAT; a2 += 256) {
      int gid = bsp * NAT + a2;
      float4 pa = ws->px[gid];
      float4 ga = ws->pg[gid];
      float ma = ga.w;
      if (ma != 0.0f) {
        float c0f = ga.x - smu[0], c1f = ga.y - smu[1], c2f = ga.z - smu[2];
        float q0 = pa.x - (sR[0]*c0f + sR[1]*c1f + sR[2]*c2f + smug[0]);
        float q1 = pa.y - (sR[3]*c0f + sR[4]*c1f + sR[5]*c2f + smug[1]);
        float q2 = pa.z - (sR[6]*c0f + sR[7]*c1f + sR[8]*c2f + smug[2]);
        msea += (double)(ws->wA[gid] * ma * (q0*q0 + q1*q1 + q2*q2));
      }
    }
    for (int off = 32; off; off >>= 1) msea += __shfl_xor(msea, off);
    if (lane == 0) dpart[wv][0] = msea;
    __syncthreads();
    if (tid == 0) {
      ws->mse_b[bsp] = dpart[0][0] + dpart[1][0] + dpart[2][0] + dpart[3][0];
      ws->red0[bsp]  = sred[0];
    }
    __syncthreads();   // dpart reused by the pair epilogue
  }

  // ---------- pair phase: 8 rows x 1024-col half per block, 2 rows per wave ----------
  int half = blk & 1;
  int rowblk = blk >> 1;
  int gid0 = rowblk * 8 + wv * 2;
  int gid1 = gid0 + 1;
  int b = gid0 >> 11;
  int a0 = gid0 & (NAT - 1), a1 = a0 + 1;

  const float4* __restrict__ pxb = ws->px + (size_t)b * NAT;
  const float4* __restrict__ pgb = ws->pg + (size_t)b * NAT;
  float4 pa0 = pxb[a0], pa1 = pxb[a1];
  float4 ga0 = pgb[a0], ga1 = pgb[a1];
  float ma0 = ga0.w, ma1 = ga1.w;
  float lm0 = ws->ligA[gid0] * ma0, lm1 = ws->ligA[gid1] * ma1;
  bool dob = (lm0 != 0.0f) || (lm1 != 0.0f);
  float th0 = (ws->nucA[gid0] > 0.5f) ? 30.0f : 15.0f;
  float th1 = (ws->nucA[gid1] > 0.5f) ? 30.0f : 15.0f;
  const float* __restrict__ tbrow0 = tb + ((size_t)b * NTOK + (__float_as_int(pa0.w) & 255)) * NTOK;
  const float* __restrict__ tbrow1 = tb + ((size_t)b * NTOK + (__float_as_int(pa1.w) & 255)) * NTOK;

  float bnum0 = 0.f, bden0 = 0.f, cem0 = 0.f, cm0 = 0.f;
  float bnum1 = 0.f, bden1 = 0.f, cem1 = 0.f, cm1 = 0.f;
  int base = half * (NAT / 2);
  #pragma unroll 4
  for (int k = 0; k < (NAT / 2) / 64; k++) {   // 16 iterations
    int c = base + 64 * k + lane;
    float4 pc = pxb[c];
    float4 gc = pgb[c];
    float d0 = pa0.x-pc.x, d1 = pa0.y-pc.y, d2 = pa0.z-pc.z;
    float dxv0 = FSQRT(d0*d0 + d1*d1 + d2*d2);
    float e0 = ga0.x-gc.x, e1 = ga0.y-gc.y, e2 = ga0.z-gc.z;
    float dgv0 = FSQRT(e0*e0 + e1*e1 + e2*e2);
    float diff0 = dxv0 - dgv0;
    float f0 = pa1.x-pc.x, f1 = pa1.y-pc.y, f2 = pa1.z-pc.z;
    float dxv1 = FSQRT(f0*f0 + f1*f1 + f2*f2);
    float h0 = ga1.x-gc.x, h1 = ga1.y-gc.y, h2 = ga1.z-gc.z;
    float dgv1 = FSQRT(h0*h0 + h1*h1 + h2*h2);
    float diff1 = dxv1 - dgv1;
    if (dob) {
      int meta = __float_as_int(pc.w);
      float pol = (meta & 256) ? 1.0f : 0.0f;   // masked cols have polbit cleared
      float tv0 = tbrow0[meta & 255] * pol;
      float tv1 = tbrow1[meta & 255] * pol;
      bnum0 += diff0 * diff0 * tv0;  bden0 += tv0;
      bnum1 += diff1 * diff1 * tv1;  bden1 += tv1;
    }
    float t0 = fminf(fabsf(diff0) * 16.0f, 255.0f);
    float t1 = fminf(fabsf(diff1) * 16.0f, 255.0f);
    int i0 = (int)t0, i1 = (int)t1;
    float2 l0 = lut[i0], l1 = lut[i1];
    float ev0 = fmaf(t0 - (float)i0, l0.y, l0.x);
    float ev1 = fmaf(t1 - (float)i1, l1.y, l1.x);
    float pml0 = (dgv0 < th0) ? 1.0f : 0.0f;  // masked cols poisoned -> dgv huge -> 0
    float pml1 = (dgv1 < th1) ? 1.0f : 0.0f;
    cem0 += ev0 * pml0;  cm0 += pml0;
    cem1 += ev1 * pml1;  cm1 += pml1;
  }
  // remove diagonal (c==a) contribution: dd=0 -> E=3.2163288, pml=1
  if ((a0 >> 10) == half && lane == (a0 & 63)) { cem0 -= 3.2163288f; cm0 -= 1.0f; }
  if ((a1 >> 10) == half && lane == (a1 & 63)) { cem1 -= 3.2163288f; cm1 -= 1.0f; }

  float vals[4] = { lm0*bnum0 + lm1*bnum1, lm0*bden0 + lm1*bden1,
                    0.25f*(ma0*cem0 + ma1*cem1), ma0*cm0 + ma1*cm1 };
  for (int k = 0; k < 4; k++)
    for (int off = 32; off; off >>= 1) vals[k] += __shfl_xor(vals[k], off);
  if (lane == 0)
    for (int k = 0; k < 4; k++) dpart[wv][k] = (double)vals[k];
  __syncthreads();
  if (tid < 4)   // plain store to private SoA slot
    ws->partials[tid * NBLK + blk] = dpart[0][tid] + dpart[1][tid] + dpart[2][tid] + dpart[3][tid];
  __syncthreads();

  // ---------- last-block combine ----------
  if (tid == 0) {
    __threadfence();                       // release our stores device-wide
    sticket = atomicAdd(&ws->ticket, 1);   // device-scope RMW
  }
  __syncthreads();
  if (sticket == NBLK - 1) {
    __threadfence();                       // acquire: invalidate stale lines
    double acc8[8];
    for (int k = 0; k < 8; k++) acc8[k] = 0.0;
    for (int s2 = tid; s2 < NBLK; s2 += 256) {
      int bb = s2 >> 9;                    // blocks 0..511 = batch 0
      for (int k = 0; k < 4; k++) acc8[bb*4+k] += ws->partials[k * NBLK + s2];
    }
    for (int k = 0; k < 8; k++)
      for (int off = 32; off; off >>= 1) acc8[k] += __shfl_xor(acc8[k], off);
    if (lane == 0)
      for (int k = 0; k < 8; k++) dpart[wv][k] = acc8[k];
    __syncthreads();
    if (tid == 0) {
      double t8[8];
      for (int k = 0; k < 8; k++)
        t8[k] = dpart[0][k] + dpart[1][k] + dpart[2][k] + dpart[3][k];
      double mse_num = ws->mse_b[0] + ws->mse_b[1];
      const double wt = (4.0*4.0 + 16.0*16.0) / ((4.0+16.0)*(4.0+16.0));  // 0.68
      double lsum = 0.0;
      for (int bb = 0; bb < BB; bb++) {
        double lmse  = mse_num / (3.0 * ws->red0[bb]);
        double lbond = t8[bb*4+0] / t8[bb*4+1];
        double lddt  = t8[bb*4+2] / t8[bb*4+3];
        lsum += wt * (lmse + lbond) + (1.0 - lddt);
      }
      out[0] = (float)(lsum / BB);
    }
  }
}

extern "C" void kernel_launch(void* const* d_in, const int* in_sizes, int n_in,
                              void* d_out, int out_size, void* d_ws, size_t ws_size,
                              hipStream_t stream) {
  const float* x    = (const float*)d_in[0];
  const float* xgt  = (const float*)d_in[1];
  const float* mask = (const float*)d_in[2];
  const float* A    = (const float*)d_in[3];
  const float* tb   = (const float*)d_in[4];
  const float* poly = (const float*)d_in[5];
  const float* lig  = (const float*)d_in[6];
  const float* dna  = (const float*)d_in[7];
  const float* rna  = (const float*)d_in[8];
  WS* ws = (WS*)d_ws;
  float* out = (float*)d_out;

  k_prep<<<NBLK, 256, 0, stream>>>(x, xgt, mask, A, poly, lig, dna, rna, ws);
  k_main<<<NBLK, 256, 0, stream>>>(tb, ws, out);
}